// Round 1
// baseline (207.352 us; speedup 1.0000x reference)
//
#include <hip/hip_runtime.h>

#define TEMP    0.5f
#define LOG2E   1.4426950408889634f
#define C2      (LOG2E / TEMP)        /* 2.8853900817779268 : t = dot * C2 */
#define MSHIFT  160.0f                /* fixed base-2 softmax shift        */
#define LN2     0.6931471805599453f
#define NROWS   16384
#define BHALF   8192
#define DDIM    128

typedef __bf16 bf16x8 __attribute__((ext_vector_type(8)));
typedef float  f32x16 __attribute__((ext_vector_type(16)));

__device__ __forceinline__ float fexp2(float x) {
#if __has_builtin(__builtin_amdgcn_exp2f)
  return __builtin_amdgcn_exp2f(x);
#else
  return exp2f(x);
#endif
}

__device__ __forceinline__ unsigned short f2bf(float f) {
  unsigned int u = __float_as_uint(f);
  unsigned int r = (u + 0x7FFFu + ((u >> 16) & 1u)) >> 16;  // RNE
  return (unsigned short)r;
}

// ---------------------------------------------------------------------------
// k_prep: fp32 -> bf16 cast of concat(z_i, z_j); zero S[16384] and P.
// grid 2048 x 256, 4 floats/thread = 2,097,152 elements exactly.
// ---------------------------------------------------------------------------
__global__ void k_prep(const float* __restrict__ zi, const float* __restrict__ zj,
                       unsigned short* __restrict__ zb,
                       float* __restrict__ S, float* __restrict__ P) {
  int g = blockIdx.x * blockDim.x + threadIdx.x;      // 0 .. 524287
  const float* src;
  int off;
  if (g < (BHALF * DDIM / 4)) { src = zi; off = g * 4; }
  else                        { src = zj; off = g * 4 - BHALF * DDIM; }
  float4 v = *reinterpret_cast<const float4*>(src + off);
  ushort4 o;
  o.x = f2bf(v.x); o.y = f2bf(v.y); o.z = f2bf(v.z); o.w = f2bf(v.w);
  *reinterpret_cast<ushort4*>(zb + (size_t)g * 4) = o;
  if (g < NROWS) S[g] = 0.f;
  if (g == 0)    P[0] = 0.f;
}

// ---------------------------------------------------------------------------
// k_pos: P = sum_k dot(z_i[k], z_j[k])  (exact fp32; Sum(pos) = 4*P)
// ---------------------------------------------------------------------------
__global__ void k_pos(const float* __restrict__ zi, const float* __restrict__ zj,
                      float* __restrict__ P) {
  int g = blockIdx.x * blockDim.x + threadIdx.x;
  float acc = 0.f;
  const float2* a2 = reinterpret_cast<const float2*>(zi);
  const float2* b2 = reinterpret_cast<const float2*>(zj);
  for (int i = g; i < BHALF * DDIM / 2; i += gridDim.x * blockDim.x) {
    float2 a = a2[i], b = b2[i];
    acc = fmaf(a.x, b.x, acc);
    acc = fmaf(a.y, b.y, acc);
  }
#pragma unroll
  for (int m = 32; m >= 1; m >>= 1) acc += __shfl_xor(acc, m, 64);
  __shared__ float red[4];
  int w = threadIdx.x >> 6, l = threadIdx.x & 63;
  if (l == 0) red[w] = acc;
  __syncthreads();
  if (threadIdx.x == 0) atomicAdd(P, red[0] + red[1] + red[2] + red[3]);
}

// ---------------------------------------------------------------------------
// k_main: flash-style Gram-GEMM + fixed-shift exp accumulation.
// Wave owns 64 rows (A frags persistent in VGPRs), sweeps 2048 cols in
// 32-col tiles. 16 x mfma_32x32x16_bf16 per tile. No LDS, no barriers.
// Partial row sums of 2^(t - M) atomically added into S.
// ---------------------------------------------------------------------------
__device__ __forceinline__ void loadB(bf16x8 (&b)[8], const unsigned short* bp) {
#pragma unroll
  for (int ks = 0; ks < 8; ++ks)
    b[ks] = *reinterpret_cast<const bf16x8*>(bp + ks * 16);
}

__device__ __forceinline__ void processTile(const bf16x8 (&a)[2][8], const bf16x8 (&b)[8],
                                            float (&s0)[16], float (&s1)[16],
                                            int row0, int c0, int lo, int hi) {
  f32x16 acc0 = {};
  f32x16 acc1 = {};
#pragma unroll
  for (int ks = 0; ks < 8; ++ks) {
    acc0 = __builtin_amdgcn_mfma_f32_32x32x16_bf16(a[0][ks], b[ks], acc0, 0, 0, 0);
    acc1 = __builtin_amdgcn_mfma_f32_32x32x16_bf16(a[1][ks], b[ks], acc1, 0, 0, 0);
  }
  if (c0 + 31 >= row0 && c0 <= row0 + 63) {
    // col tile intersects this wave's rows: mask the diagonal
    const int col = c0 + lo;
#pragma unroll
    for (int r = 0; r < 16; ++r) {
      const int rloc = (r & 3) + 8 * (r >> 2) + 4 * hi;   // C/D row (HW-verified)
      float e0 = fexp2(fmaf(acc0[r], C2, -MSHIFT));
      float e1 = fexp2(fmaf(acc1[r], C2, -MSHIFT));
      if (row0 + rloc == col)      e0 = 0.f;
      if (row0 + 32 + rloc == col) e1 = 0.f;
      s0[r] += e0;
      s1[r] += e1;
    }
  } else {
#pragma unroll
    for (int r = 0; r < 16; ++r) {
      s0[r] += fexp2(fmaf(acc0[r], C2, -MSHIFT));
      s1[r] += fexp2(fmaf(acc1[r], C2, -MSHIFT));
    }
  }
}

__global__ __launch_bounds__(256, 2)
void k_main(const unsigned short* __restrict__ zb, float* __restrict__ S) {
  const int wave = threadIdx.x >> 6;
  const int lane = threadIdx.x & 63;
  const int lo = lane & 31;
  const int hi = lane >> 5;
  const int rb = blockIdx.x & 63;       // 64 row blocks of 256 rows
  const int cs = blockIdx.x >> 6;       // 8 col chunks of 2048 cols
  const int row0 = rb * 256 + wave * 64;

  // A fragments: 64 rows x 128 K, persistent in registers (64 VGPRs)
  bf16x8 a[2][8];
#pragma unroll
  for (int rt = 0; rt < 2; ++rt) {
    const unsigned short* ap = zb + (size_t)(row0 + rt * 32 + lo) * DDIM + hi * 8;
#pragma unroll
    for (int ks = 0; ks < 8; ++ks)
      a[rt][ks] = *reinterpret_cast<const bf16x8*>(ap + ks * 16);
  }

  float s0[16], s1[16];
#pragma unroll
  for (int r = 0; r < 16; ++r) { s0[r] = 0.f; s1[r] = 0.f; }

  const int c0base = cs * 2048;
  const unsigned short* bbase = zb + (size_t)(c0base + lo) * DDIM + hi * 8;

  bf16x8 b0[8], b1[8];
  loadB(b0, bbase);
  for (int it = 0; it < 64; it += 2) {
    loadB(b1, bbase + (size_t)(it + 1) * 32 * DDIM);          // prefetch odd tile
    processTile(a, b0, s0, s1, row0, c0base + it * 32, lo, hi);
    if (it + 2 < 64)
      loadB(b0, bbase + (size_t)(it + 2) * 32 * DDIM);        // prefetch next even
    processTile(a, b1, s0, s1, row0, c0base + (it + 1) * 32, lo, hi);
  }

  // reduce each row's 32 column-lanes, then one atomic per row
#pragma unroll
  for (int r = 0; r < 16; ++r) {
    float v0 = s0[r], v1 = s1[r];
#pragma unroll
    for (int m = 16; m >= 1; m >>= 1) {
      v0 += __shfl_xor(v0, m, 64);    // masks <32 stay within each 32-lane half
      v1 += __shfl_xor(v1, m, 64);
    }
    if (lo == 0) {
      const int rloc = (r & 3) + 8 * (r >> 2) + 4 * hi;
      atomicAdd(&S[row0 + rloc],      v0);
      atomicAdd(&S[row0 + 32 + rloc], v1);
    }
  }
}

// ---------------------------------------------------------------------------
// k_fin: loss = ( LN2 * sum_k (M + log2 S_k)  -  4*P ) / N
// ---------------------------------------------------------------------------
__global__ void k_fin(const float* __restrict__ S, const float* __restrict__ P,
                      float* __restrict__ out) {
  int t = threadIdx.x;
  float local = 0.f;
  for (int r = t; r < NROWS; r += 256)
    local += MSHIFT + __log2f(S[r]);
  __shared__ float red[256];
  red[t] = local;
  __syncthreads();
  for (int s2 = 128; s2 > 0; s2 >>= 1) {
    if (t < s2) red[t] += red[t + s2];
    __syncthreads();
  }
  if (t == 0)
    out[0] = (LN2 * red[0] - 4.0f * P[0]) / (float)NROWS;
}

// ---------------------------------------------------------------------------
extern "C" void kernel_launch(void* const* d_in, const int* in_sizes, int n_in,
                              void* d_out, int out_size, void* d_ws, size_t ws_size,
                              hipStream_t stream) {
  const float* zi = (const float*)d_in[0];
  const float* zj = (const float*)d_in[1];
  unsigned short* zb = (unsigned short*)d_ws;                        // 4 MB bf16 Z
  float* S = (float*)((char*)d_ws + (size_t)NROWS * DDIM * 2);       // 64 KB
  float* P = S + NROWS;                                              // 4 B
  float* out = (float*)d_out;

  hipLaunchKernelGGL(k_prep, dim3(2048), dim3(256), 0, stream, zi, zj, zb, S, P);
  hipLaunchKernelGGL(k_pos,  dim3(256),  dim3(256), 0, stream, zi, zj, P);
  hipLaunchKernelGGL(k_main, dim3(512),  dim3(256), 0, stream, zb, S);
  hipLaunchKernelGGL(k_fin,  dim3(1),    dim3(256), 0, stream, S, P, out);
}

// Round 2
// 134.584 us; speedup vs baseline: 1.5407x; 1.5407x over previous
//
#include <hip/hip_runtime.h>

#define TEMP    0.5f
#define LOG2E   1.4426950408889634f
#define C2      (LOG2E / TEMP)        /* t = dot * C2 */
#define MSHIFT  160.0f                /* fixed base-2 softmax shift */
#define LN2     0.6931471805599453f
#define NROWS   16384
#define BHALF   8192
#define DDIM    128
#define PREPB   2048                  /* k_prep blocks = 524288/256 */

typedef __bf16 bf16x8 __attribute__((ext_vector_type(8)));
typedef float  f32x16 __attribute__((ext_vector_type(16)));

__device__ __forceinline__ float fexp2(float x) {
#if __has_builtin(__builtin_amdgcn_exp2f)
  return __builtin_amdgcn_exp2f(x);
#else
  return exp2f(x);
#endif
}

__device__ __forceinline__ unsigned short f2bf(float f) {
  unsigned int u = __float_as_uint(f);
  unsigned int r = (u + 0x7FFFu + ((u >> 16) & 1u)) >> 16;  // RNE
  return (unsigned short)r;
}

// ---------------------------------------------------------------------------
// zbF frag-major layout: for row r, k-index k:
//   g = r/32, lo = r%32, khi = k/8, j = k%8
//   short index = g*4096 + khi*256 + lo*8 + j
// A wave's frag load (fixed ks): 64 lanes read a contiguous 1KB block.
// ---------------------------------------------------------------------------

// k_prep: cast concat(z_i,z_j) fp32->bf16 into frag-major zbF; per-block
// partial dot(z_i,z_j) -> Pp[block]; zero S. Fuses old k_prep + k_pos.
__global__ void k_prep(const float* __restrict__ zi, const float* __restrict__ zj,
                       unsigned short* __restrict__ zbF,
                       float* __restrict__ S, float* __restrict__ Pp) {
  const int t   = blockIdx.x * 256 + threadIdx.x;   // 0..524287 float4 groups
  const int row = t >> 5;                           // 32 float4 per 128-elt row
  const int k0  = (t & 31) * 4;
  const float* src = (row < BHALF) ? (zi + (size_t)row * DDIM)
                                   : (zj + (size_t)(row - BHALF) * DDIM);
  float4 v = *reinterpret_cast<const float4*>(src + k0);

  const int g = row >> 5, lo = row & 31, khi = k0 >> 3, j0 = k0 & 7;
  ushort4 o;
  o.x = f2bf(v.x); o.y = f2bf(v.y); o.z = f2bf(v.z); o.w = f2bf(v.w);
  *reinterpret_cast<ushort4*>(zbF + (size_t)g * 4096 + khi * 256 + lo * 8 + j0) = o;

  float dot = 0.f;
  if (row < BHALF) {
    float4 w = *reinterpret_cast<const float4*>(zj + (size_t)row * DDIM + k0);
    dot = fmaf(v.x, w.x, fmaf(v.y, w.y, fmaf(v.z, w.z, v.w * w.w)));
  }
#pragma unroll
  for (int m = 32; m >= 1; m >>= 1) dot += __shfl_xor(dot, m, 64);
  __shared__ float red[4];
  if ((threadIdx.x & 63) == 0) red[threadIdx.x >> 6] = dot;
  __syncthreads();
  if (threadIdx.x == 0) Pp[blockIdx.x] = red[0] + red[1] + red[2] + red[3];

  if (t < NROWS) S[t] = 0.f;
}

// ---------------------------------------------------------------------------
// k_main: wave holds 128 persistent rows as MFMA *B* operand (lane-indexed in
// C/D -> scalar row sums). Streams 32-col tiles as the A operand, coalesced
// frag loads from frag-major zbF. Single-buffer pipelined reload under the
// exp section. No LDS, no barriers.
// ---------------------------------------------------------------------------
template <bool MASK>
__device__ __forceinline__ void expAcc(const f32x16& acc, float& sa, float& sb,
                                       int d, int hi) {
#pragma unroll
  for (int r = 0; r < 16; ++r) {
    float e = fexp2(fmaf(acc[r], C2, -MSHIFT));
    if (MASK) {
      const int rloc = (r & 3) + 8 * (r >> 2) + 4 * hi;  // col-part (C/D reg map)
      if (rloc == d) e = 0.f;
    }
    if (r & 1) sb += e; else sa += e;
  }
}

__global__ __launch_bounds__(256, 2)
void k_main(const unsigned short* __restrict__ zbF, float* __restrict__ S) {
  const int wave = threadIdx.x >> 6;
  const int lane = threadIdx.x & 63;
  const int lo = lane & 31;
  const int hi = lane >> 5;
  const int rb = blockIdx.x & 31;       // 32 row blocks of 512 rows
  const int cc = blockIdx.x >> 5;       // 16 col chunks of 1024 cols
  const int row0w = rb * 512 + wave * 128;

  // persistent row frags (B operand): 4 row-tiles x 8 k-steps = 128 VGPRs
  bf16x8 b[4][8];
#pragma unroll
  for (int rt = 0; rt < 4; ++rt) {
    const unsigned short* bp = zbF + (size_t)((row0w >> 5) + rt) * 4096 + hi * 256 + lo * 8;
#pragma unroll
    for (int ks = 0; ks < 8; ++ks)
      b[rt][ks] = *reinterpret_cast<const bf16x8*>(bp + ks * 512);
  }

  const f32x16 kZ = {};                 // persistent zero C-operand
  float s[4][2];
#pragma unroll
  for (int rt = 0; rt < 4; ++rt) { s[rt][0] = 0.f; s[rt][1] = 0.f; }

  const int c0base = cc * 1024;
  const unsigned short* abase = zbF + (size_t)(c0base >> 5) * 4096 + hi * 256 + lo * 8;

  bf16x8 a[8];
#pragma unroll
  for (int ks = 0; ks < 8; ++ks)
    a[ks] = *reinterpret_cast<const bf16x8*>(abase + ks * 512);

  for (int it = 0; it < 32; ++it) {
    const int c0 = c0base + it * 32;
    const int dr = c0 - row0w;
    const bool dg = (unsigned)dr < 128u;       // tile touches diagonal?
    const int rtd = dg ? (dr >> 5) : -1;

    // half 1: row-tiles 0,1
    f32x16 acc0 = __builtin_amdgcn_mfma_f32_32x32x16_bf16(a[0], b[0][0], kZ, 0, 0, 0);
    f32x16 acc1 = __builtin_amdgcn_mfma_f32_32x32x16_bf16(a[0], b[1][0], kZ, 0, 0, 0);
#pragma unroll
    for (int ks = 1; ks < 8; ++ks) {
      acc0 = __builtin_amdgcn_mfma_f32_32x32x16_bf16(a[ks], b[0][ks], acc0, 0, 0, 0);
      acc1 = __builtin_amdgcn_mfma_f32_32x32x16_bf16(a[ks], b[1][ks], acc1, 0, 0, 0);
    }
    if (!dg) {
      expAcc<false>(acc0, s[0][0], s[0][1], -1, hi);
      expAcc<false>(acc1, s[1][0], s[1][1], -1, hi);
    } else {
      expAcc<true>(acc0, s[0][0], s[0][1], rtd == 0 ? lo : -1, hi);
      expAcc<true>(acc1, s[1][0], s[1][1], rtd == 1 ? lo : -1, hi);
    }

    // half 2: row-tiles 2,3
    acc0 = __builtin_amdgcn_mfma_f32_32x32x16_bf16(a[0], b[2][0], kZ, 0, 0, 0);
    acc1 = __builtin_amdgcn_mfma_f32_32x32x16_bf16(a[0], b[3][0], kZ, 0, 0, 0);
#pragma unroll
    for (int ks = 1; ks < 8; ++ks) {
      acc0 = __builtin_amdgcn_mfma_f32_32x32x16_bf16(a[ks], b[2][ks], acc0, 0, 0, 0);
      acc1 = __builtin_amdgcn_mfma_f32_32x32x16_bf16(a[ks], b[3][ks], acc1, 0, 0, 0);
    }

    // pipelined single-buffer reload: a[] free after the chains above; the
    // vmcnt wait lands after the ~900-cyc exp section below.
    if (it + 1 < 32) {
      const unsigned short* ap = abase + (size_t)(it + 1) * 4096;
#pragma unroll
      for (int ks = 0; ks < 8; ++ks)
        a[ks] = *reinterpret_cast<const bf16x8*>(ap + ks * 512);
    }

    if (!dg) {
      expAcc<false>(acc0, s[2][0], s[2][1], -1, hi);
      expAcc<false>(acc1, s[3][0], s[3][1], -1, hi);
    } else {
      expAcc<true>(acc0, s[2][0], s[2][1], rtd == 2 ? lo : -1, hi);
      expAcc<true>(acc1, s[3][0], s[3][1], rtd == 3 ? lo : -1, hi);
    }
  }

  // row sums: lane-local scalar + fold hi halves, one atomic per row per chunk
#pragma unroll
  for (int rt = 0; rt < 4; ++rt) {
    float v = s[rt][0] + s[rt][1];
    v += __shfl_xor(v, 32, 64);
    if (hi == 0) atomicAdd(&S[row0w + rt * 32 + lo], v);
  }
}

// ---------------------------------------------------------------------------
// k_fin: out = ( LN2 * sum_k (M + log2 S_k)  -  4 * sum Pp ) / N
// Linear -> single fused block reduction.
// ---------------------------------------------------------------------------
__global__ void k_fin(const float* __restrict__ S, const float* __restrict__ Pp,
                      float* __restrict__ out) {
  const int t = threadIdx.x;            // 512 threads
  float q = 0.f;
  for (int r = t; r < NROWS; r += 512)
    q += LN2 * (MSHIFT + __log2f(S[r]));
  for (int r = t; r < PREPB; r += 512)
    q -= 4.0f * Pp[r];
  __shared__ float red[512];
  red[t] = q;
  __syncthreads();
  for (int s2 = 256; s2 > 0; s2 >>= 1) {
    if (t < s2) red[t] += red[t + s2];
    __syncthreads();
  }
  if (t == 0) out[0] = red[0] / (float)NROWS;
}

// ---------------------------------------------------------------------------
extern "C" void kernel_launch(void* const* d_in, const int* in_sizes, int n_in,
                              void* d_out, int out_size, void* d_ws, size_t ws_size,
                              hipStream_t stream) {
  const float* zi = (const float*)d_in[0];
  const float* zj = (const float*)d_in[1];
  unsigned short* zbF = (unsigned short*)d_ws;                     // 4 MB
  float* S  = (float*)((char*)d_ws + (size_t)NROWS * DDIM * 2);    // 64 KB
  float* Pp = S + NROWS;                                           // 8 KB
  float* out = (float*)d_out;

  hipLaunchKernelGGL(k_prep, dim3(PREPB), dim3(256), 0, stream, zi, zj, zbF, S, Pp);
  hipLaunchKernelGGL(k_main, dim3(512),  dim3(256), 0, stream, zbF, S);
  hipLaunchKernelGGL(k_fin,  dim3(1),    dim3(512), 0, stream, S, Pp, out);
}